// Round 19
// baseline (159.519 us; speedup 1.0000x reference)
//
#include <hip/hip_runtime.h>
#include <hip/hip_bf16.h>

#define HID 128

typedef __attribute__((ext_vector_type(8))) short short8;
typedef __attribute__((ext_vector_type(4))) float f32x4;
typedef __attribute__((ext_vector_type(16))) float f32x16;
typedef __attribute__((ext_vector_type(4))) unsigned int u32x4;
typedef __attribute__((ext_vector_type(2))) _Float16 h2;

__device__ __forceinline__ short f2bf(float x) {
    __bf16 b = (__bf16)x;
    return __builtin_bit_cast(short, b);
}

// ===========================================================================
// FACTORED PATH: U = emb@W1[:128], V = emb@W1[128:] (dense per-node GEMM),
// then out[e] = relu(U[src]+V[tgt]+b1)@W2 + b2 (gather + packed-fp16 VALU).
// R19 = R18 with the scatter rank bug fixed: lo[wv][b] is now the PER-BUCKET
// cross-wave prefix (R18's 32-wide scan wrongly summed across buckets ->
// OOB rec[] writes -> crash).
// ===========================================================================

// ---------------------------------------------------------------------------
// Fused: blocks 0..15 pack W1 halves into 32x32x16 MFMA-B fragment order;
// ALL blocks histogram tgt into 8 buckets (gh pre-zeroed via memset).
// ---------------------------------------------------------------------------
__global__ __launch_bounds__(256) void hist_pack_kernel(
    const float* __restrict__ W1, short* __restrict__ bpk2,
    const void* __restrict__ src_raw, const void* __restrict__ tgt_raw,
    int E, float bscale, int* __restrict__ gh)
{
    const int tid = threadIdx.x;

    if (blockIdx.x < 16) {
        int t = blockIdx.x * 256 + tid;   // 0..4095 = half*2048 + nt*512 + ks*64 + l
        int l    = t & 63;
        int ks   = (t >> 6) & 7;
        int nt   = (t >> 9) & 3;
        int half = t >> 11;
        int k0  = half * 128 + ks * 16 + (l >> 5) * 8;
        int col = nt * 32 + (l & 31);
        short8 v;
#pragma unroll
        for (int j = 0; j < 8; ++j)
            v[j] = f2bf(W1[(k0 + j) * HID + col]);
        *reinterpret_cast<short8*>(&bpk2[t * 8]) = v;
    }

    __shared__ int lh[8];
    if (tid < 8) lh[tid] = 0;
    __syncthreads();

    int i64f = 1;
    {
        const int* s32 = (const int*)src_raw;
#pragma unroll
        for (int i = 1; i < 32; i += 2) i64f &= (s32[i] == 0);
    }
    const int stride = gridDim.x * 256;
    for (int e = blockIdx.x * 256 + tid; e < E; e += stride) {
        int t = i64f ? (int)((const long long*)tgt_raw)[e]
                     : ((const int*)tgt_raw)[e];
        int b = (int)((float)t * bscale);
        b = b < 0 ? 0 : (b > 7 ? 7 : b);
        atomicAdd(&lh[b], 1);
    }
    __syncthreads();
    if (tid < 8 && lh[tid]) atomicAdd(&gh[tid], lh[tid]);
}

// ---------------------------------------------------------------------------
// UV precompute (fp16 output): mfma_f32_32x32x16_bf16, 128 nodes/block.
// ---------------------------------------------------------------------------
__global__ __launch_bounds__(512, 4) void uv_kernel(
    const float* __restrict__ emb,
    const short* __restrict__ bpk2,
    unsigned short* __restrict__ U,
    unsigned short* __restrict__ V,
    int Nn)
{
    __shared__ short lds_b[32768];

    const int tid = threadIdx.x;
    const int l   = tid & 63;
    const int wid = tid >> 6;
    const int wg  = wid >> 1;
    const int wn  = wid & 1;
    const int lc  = l & 31;
    const int hi  = l >> 5;

    {
        const u32x4* g = (const u32x4*)bpk2;
        u32x4* d = (u32x4*)lds_b;
#pragma unroll
        for (int i = 0; i < 8; ++i) d[i * 512 + tid] = g[i * 512 + tid];
    }
    __syncthreads();

    const int base = blockIdx.x * 128 + wg * 32;
    int nr = base + lc;
    if (nr >= Nn) nr = Nn - 1;

    f32x16 accU[2], accV[2];
#pragma unroll
    for (int n = 0; n < 2; ++n) { accU[n] = (f32x16)(0.f); accV[n] = (f32x16)(0.f); }

#pragma unroll
    for (int ks = 0; ks < 8; ++ks) {
        const float* p = emb + (size_t)nr * HID + ks * 16 + hi * 8;
        f32x4 x0 = *reinterpret_cast<const f32x4*>(p);
        f32x4 x1 = *reinterpret_cast<const f32x4*>(p + 4);
        short8 afr;
#pragma unroll
        for (int j = 0; j < 4; ++j) { afr[j] = f2bf(x0[j]); afr[4 + j] = f2bf(x1[j]); }
#pragma unroll
        for (int n = 0; n < 2; ++n) {
            const int nt = wn * 2 + n;
            short8 bU = *reinterpret_cast<const short8*>(&lds_b[(((0 + nt) * 8 + ks) * 64 + l) * 8]);
            short8 bV = *reinterpret_cast<const short8*>(&lds_b[(((4 + nt) * 8 + ks) * 64 + l) * 8]);
            accU[n] = __builtin_amdgcn_mfma_f32_32x32x16_bf16(afr, bU, accU[n], 0, 0, 0);
            accV[n] = __builtin_amdgcn_mfma_f32_32x32x16_bf16(afr, bV, accV[n], 0, 0, 0);
        }
    }

#pragma unroll
    for (int n = 0; n < 2; ++n) {
        const int col = wn * 64 + n * 32 + lc;
#pragma unroll
        for (int r = 0; r < 16; ++r) {
            const int row = (r & 3) + 8 * (r >> 2) + 4 * hi;
            const int node = base + row;
            if (node < Nn) {
                _Float16 hu = (_Float16)accU[n][r];
                _Float16 hv = (_Float16)accV[n][r];
                U[(size_t)node * HID + col] = __builtin_bit_cast(unsigned short, hu);
                V[(size_t)node * HID + col] = __builtin_bit_cast(unsigned short, hv);
            }
        }
    }
}

// ---------------------------------------------------------------------------
// Ballot-rank counting-sort scatter into 8 bucket regions. 2048 edges/block.
// rec = e | (s<<21) | (t<<38) (requires E<2^21, Nn<2^17).
// pos = go[b] (gh scan) + grb[b] (block reservation) + lo[w][b] (cross-wave
// per-bucket prefix) + wrun[b] (intra-wave running) + ballot rank.
// ---------------------------------------------------------------------------
__global__ __launch_bounds__(256) void scatter8_kernel(
    const void* __restrict__ src_raw, const void* __restrict__ tgt_raw,
    int E, float bscale,
    const int* __restrict__ gh, int* __restrict__ cursor,
    unsigned long long* __restrict__ rec)
{
    __shared__ int wcnt_lds[4][8];
    __shared__ int lo[4][8];
    __shared__ int grb[8];
    __shared__ int go[8];

    const int tid = threadIdx.x;
    const int l   = tid & 63;
    const int w   = tid >> 6;

    int i64f = 1;
    {
        const int* s32 = (const int*)src_raw;
#pragma unroll
        for (int i = 1; i < 32; i += 2) i64f &= (s32[i] == 0);
    }

    if (tid < 8) {
        int v = gh[tid];
        int inc = v;
#pragma unroll
        for (int off = 1; off < 8; off <<= 1) {
            int x = __shfl_up(inc, off, 8);
            if (tid >= off) inc += x;
        }
        go[tid] = inc - v;
    }

    const int base = blockIdx.x * 2048;
    int myS[8], myT[8], myB[8];
#pragma unroll
    for (int k = 0; k < 8; ++k) {
        const int e = base + k * 256 + tid;
        myB[k] = -1;
        if (e < E) {
            int s, t;
            if (i64f) {
                s = (int)((const long long*)src_raw)[e];
                t = (int)((const long long*)tgt_raw)[e];
            } else {
                s = ((const int*)src_raw)[e];
                t = ((const int*)tgt_raw)[e];
            }
            int b = (int)((float)t * bscale);
            b = b < 0 ? 0 : (b > 7 ? 7 : b);
            myS[k] = s; myT[k] = t; myB[k] = b;
        }
    }

    // ---- count: per-wave per-bucket totals via ballots (uniform per wave)
    int wcnt[8];
#pragma unroll
    for (int b = 0; b < 8; ++b) wcnt[b] = 0;
#pragma unroll
    for (int k = 0; k < 8; ++k) {
#pragma unroll
        for (int b = 0; b < 8; ++b) {
            unsigned long long m = __ballot(myB[k] == b);
            wcnt[b] += (int)__popcll(m);
        }
    }
    if (l < 8) wcnt_lds[w][l] = wcnt[l];
    __syncthreads();

    // ---- per-bucket cross-wave exclusive prefix (FIX vs R18: do NOT sum
    //      across buckets; grb[b] already anchors the bucket region)
    if (tid < 8) {
        const int c0 = wcnt_lds[0][tid];
        const int c1 = wcnt_lds[1][tid];
        const int c2 = wcnt_lds[2][tid];
        const int c3 = wcnt_lds[3][tid];
        lo[0][tid] = 0;
        lo[1][tid] = c0;
        lo[2][tid] = c0 + c1;
        lo[3][tid] = c0 + c1 + c2;
        const int bc = c0 + c1 + c2 + c3;
        grb[tid] = (bc > 0) ? atomicAdd(&cursor[tid], bc) : 0;
    }
    __syncthreads();

    // ---- write: rank via masked ballot popcount
    const unsigned long long ltmask = (l == 63) ? (~0ull >> 1) : ((1ull << l) - 1);
    int wrun[8];
#pragma unroll
    for (int b = 0; b < 8; ++b) wrun[b] = 0;
#pragma unroll
    for (int k = 0; k < 8; ++k) {
#pragma unroll
        for (int b = 0; b < 8; ++b) {
            unsigned long long m = __ballot(myB[k] == b);
            if (myB[k] == b) {
                const int rank = (int)__popcll(m & ltmask);
                const int pos = go[b] + grb[b] + lo[w][b] + wrun[b] + rank;
                rec[pos] = (unsigned long long)(unsigned)(base + k * 256 + tid)
                         | ((unsigned long long)(unsigned)myS[k] << 21)
                         | ((unsigned long long)(unsigned)myT[k] << 38);
            }
            wrun[b] += (int)__popcll(m);
        }
    }
}

// ---------------------------------------------------------------------------
// Partitioned edge pass: XCD p (blockIdx%8, round-robin dispatch) processes
// bucket p = [off[p], off[p+1]); off derived in-block from gh[8]. 8 edge-
// groups per wave = 16 outstanding 16B gathers/lane. fp16 packed math.
// ---------------------------------------------------------------------------
__global__ __launch_bounds__(256) void edge_pass_part_kernel(
    const unsigned short* __restrict__ U,
    const unsigned short* __restrict__ V,
    const unsigned long long* __restrict__ rec,
    const int* __restrict__ gh,
    const float* __restrict__ b1,
    const float* __restrict__ W2,
    const float* __restrict__ b2,
    float* __restrict__ out,
    int per_x)
{
    __shared__ int sh_off[9];

    const int tid = threadIdx.x;
    if (tid < 8) {
        int v = gh[tid];
        int inc = v;
#pragma unroll
        for (int off = 1; off < 8; off <<= 1) {
            int x = __shfl_up(inc, off, 8);
            if (tid >= off) inc += x;
        }
        sh_off[tid] = inc - v;
        if (tid == 7) sh_off[8] = inc;
    }
    __syncthreads();

    const int l   = tid & 63;
    const int wid = tid >> 6;
    const int le  = l >> 4;          // edge slot in group (0..3)
    const int lc  = l & 15;          // col group: cols [lc*8, lc*8+8)
    const int p   = blockIdx.x & 7;  // XCD (round-robin dispatch)
    const int r   = blockIdx.x >> 3;

    const int pbeg = sh_off[p];
    const int pend = sh_off[p + 1];

    h2 b1p[4], w2p[4];
    {
        f32x4 a = *reinterpret_cast<const f32x4*>(b1 + lc * 8);
        f32x4 b = *reinterpret_cast<const f32x4*>(b1 + lc * 8 + 4);
        f32x4 c = *reinterpret_cast<const f32x4*>(W2 + lc * 8);
        f32x4 d = *reinterpret_cast<const f32x4*>(W2 + lc * 8 + 4);
#pragma unroll
        for (int j = 0; j < 2; ++j) {
            b1p[0][j] = (_Float16)a[j];     b1p[1][j] = (_Float16)a[2 + j];
            b1p[2][j] = (_Float16)b[j];     b1p[3][j] = (_Float16)b[2 + j];
            w2p[0][j] = (_Float16)c[j];     w2p[1][j] = (_Float16)c[2 + j];
            w2p[2][j] = (_Float16)d[j];     w2p[3][j] = (_Float16)d[2 + j];
        }
    }
    const float b2s = b2[0];
    const h2 zero2 = (h2)((_Float16)0.f);

    for (int base = pbeg + r * 128; base < pend; base += per_x * 128) {
        short8 ub[8], vb[8];
        int oid[8];
        bool live[8];
#pragma unroll
        for (int g = 0; g < 8; ++g) {
            int pos = base + wid * 32 + g * 4 + le;
            live[g] = (pos < pend);
            if (!live[g]) pos = base;
            const unsigned long long rc = rec[pos];
            oid[g] = (int)(rc & 0x1FFFFF);
            const unsigned s = (unsigned)((rc >> 21) & 0x1FFFF);
            const unsigned t = (unsigned)(rc >> 38);
            ub[g] = *reinterpret_cast<const short8*>(U + s * HID + lc * 8);
            vb[g] = *reinterpret_cast<const short8*>(V + t * HID + lc * 8);
        }

#pragma unroll
        for (int g = 0; g < 8; ++g) {
            const unsigned int* uw = (const unsigned int*)&ub[g];
            const unsigned int* vw = (const unsigned int*)&vb[g];
            h2 s2 = zero2;
#pragma unroll
            for (int j = 0; j < 4; ++j) {
                h2 hu = __builtin_bit_cast(h2, uw[j]);
                h2 hv = __builtin_bit_cast(h2, vw[j]);
                h2 h  = hu + hv + b1p[j];
                h = __builtin_elementwise_max(h, zero2);
                s2 = s2 + h * w2p[j];
            }
            float s = (float)s2[0] + (float)s2[1];
#pragma unroll
            for (int w = 1; w < 16; w <<= 1)
                s += __shfl_xor(s, w, 16);
            if (lc == 0 && live[g])
                out[oid[g]] = s + b2s;
        }
    }
}

// ---------------------------------------------------------------------------
// Unsorted edge pass (R12 path, fallback).
// ---------------------------------------------------------------------------
__global__ __launch_bounds__(256) void edge_pass_kernel(
    const unsigned short* __restrict__ U,
    const unsigned short* __restrict__ V,
    const void* __restrict__ src_raw,
    const void* __restrict__ tgt_raw,
    const float* __restrict__ b1,
    const float* __restrict__ W2,
    const float* __restrict__ b2,
    float* __restrict__ out,
    int E)
{
    const int tid = threadIdx.x;
    const int l   = tid & 63;
    const int wid = tid >> 6;
    const int le  = l >> 4;
    const int lc  = l & 15;

    int oddw = 0;
    {
        const int* s32 = (const int*)src_raw;
        if (l < 32) oddw = s32[2 * l + 1];
    }
    const bool i64f = (__ballot(oddw != 0) == 0ULL);

    h2 b1p[4], w2p[4];
    {
        f32x4 a = *reinterpret_cast<const f32x4*>(b1 + lc * 8);
        f32x4 b = *reinterpret_cast<const f32x4*>(b1 + lc * 8 + 4);
        f32x4 c = *reinterpret_cast<const f32x4*>(W2 + lc * 8);
        f32x4 d = *reinterpret_cast<const f32x4*>(W2 + lc * 8 + 4);
#pragma unroll
        for (int j = 0; j < 2; ++j) {
            b1p[0][j] = (_Float16)a[j];     b1p[1][j] = (_Float16)a[2 + j];
            b1p[2][j] = (_Float16)b[j];     b1p[3][j] = (_Float16)b[2 + j];
            w2p[0][j] = (_Float16)c[j];     w2p[1][j] = (_Float16)c[2 + j];
            w2p[2][j] = (_Float16)d[j];     w2p[3][j] = (_Float16)d[2 + j];
        }
    }
    const float b2s = b2[0];
    const h2 zero2 = (h2)((_Float16)0.f);

    const long long ebase = ((long long)blockIdx.x * 4 + wid) * 16;

    short8 ub[4], vb[4];
#pragma unroll
    for (int g = 0; g < 4; ++g) {
        long long e = ebase + g * 4 + le;
        if (e >= E) e = E - 1;
        long long si, ti;
        if (i64f) {
            si = ((const long long*)src_raw)[e];
            ti = ((const long long*)tgt_raw)[e];
        } else {
            si = ((const int*)src_raw)[e];
            ti = ((const int*)tgt_raw)[e];
        }
        ub[g] = *reinterpret_cast<const short8*>(U + (unsigned)si * HID + lc * 8);
        vb[g] = *reinterpret_cast<const short8*>(V + (unsigned)ti * HID + lc * 8);
    }

#pragma unroll
    for (int g = 0; g < 4; ++g) {
        const unsigned int* uw = (const unsigned int*)&ub[g];
        const unsigned int* vw = (const unsigned int*)&vb[g];
        h2 s2 = zero2;
#pragma unroll
        for (int j = 0; j < 4; ++j) {
            h2 hu = __builtin_bit_cast(h2, uw[j]);
            h2 hv = __builtin_bit_cast(h2, vw[j]);
            h2 h  = hu + hv + b1p[j];
            h = __builtin_elementwise_max(h, zero2);
            s2 = s2 + h * w2p[j];
        }
        float s = (float)s2[0] + (float)s2[1];
#pragma unroll
        for (int w = 1; w < 16; w <<= 1)
            s += __shfl_xor(s, w, 16);
        const long long e = ebase + g * 4 + le;
        if (lc == 0 && e < E)
            out[e] = s + b2s;
    }
}

// ===========================================================================
// FALLBACK PATH (R3): MFMA over gathered rows (bf16), for tiny ws.
// ===========================================================================

__global__ void pack_w1_kernel(const float* __restrict__ W1, short* __restrict__ bpk) {
    int t = blockIdx.x * 256 + threadIdx.x;
    int f = (t >> 6) & 7;
    int l = t & 63;
    int n = t >> 9;
    int c = l & 15, kb = l >> 4;
    int k0 = f * 32 + kb * 8;
    short8 v;
#pragma unroll
    for (int j = 0; j < 8; ++j)
        v[j] = f2bf(W1[(k0 + j) * HID + n * 16 + c]);
    *reinterpret_cast<short8*>(&bpk[t * 8]) = v;
}

__global__ __launch_bounds__(256) void conv_emb_kernel(
    const float* __restrict__ emb, short* __restrict__ bemb, int n8) {
    int i = blockIdx.x * 256 + threadIdx.x;
    if (i >= n8) return;
    f32x4 x0 = *reinterpret_cast<const f32x4*>(emb + (size_t)i * 8);
    f32x4 x1 = *reinterpret_cast<const f32x4*>(emb + (size_t)i * 8 + 4);
    short8 v;
#pragma unroll
    for (int j = 0; j < 4; ++j) {
        v[j]     = f2bf(x0[j]);
        v[4 + j] = f2bf(x1[j]);
    }
    *reinterpret_cast<short8*>(&bemb[(size_t)i * 8]) = v;
}

template <int MODE>
__global__ __launch_bounds__(512, 4) void edge_head_kernel(
    const float* __restrict__ emb,
    const short* __restrict__ bemb,
    const void* __restrict__ src_raw,
    const void* __restrict__ tgt_raw,
    const float* __restrict__ W1,
    const float* __restrict__ b1,
    const float* __restrict__ W2,
    const float* __restrict__ b2,
    const short* __restrict__ bpk,
    float* __restrict__ out,
    int E)
{
    __shared__ short lds_b[32768];

    const int tid = threadIdx.x;

    int i64f = 1;
    {
        const int* s32 = (const int*)src_raw;
#pragma unroll
        for (int i = 1; i < 32; i += 2) i64f &= (s32[i] == 0);
    }

    if (MODE != 2) {
        const u32x4* g = (const u32x4*)bpk;
        u32x4* d = (u32x4*)lds_b;
#pragma unroll
        for (int i = 0; i < 8; ++i) d[i * 512 + tid] = g[i * 512 + tid];
    } else {
        for (int i = 0; i < 64; ++i) {
            int idx = i * 512 + tid;
            int col = idx & 127;
            int k   = idx >> 7;
            int n = col >> 4, cc = col & 15;
            int f = k >> 5, kb = (k >> 3) & 3, j = k & 7;
            int l2 = kb * 16 + cc;
            lds_b[(((n * 8 + f) * 64 + l2) << 3) + j] = f2bf(W1[idx]);
        }
    }
    __syncthreads();

    const int l = tid & 63;
    const int wid = tid >> 6;
    const int c = l & 15;
    const int g = l >> 4;
    const long long e0 = (long long)blockIdx.x * 256 + wid * 32;

    unsigned so[2], to[2];
#pragma unroll
    for (int m = 0; m < 2; ++m) {
        long long e = e0 + m * 16 + c;
        if (e >= E) e = E - 1;
        long long si, ti;
        if (i64f) {
            si = ((const long long*)src_raw)[e];
            ti = ((const long long*)tgt_raw)[e];
        } else {
            si = ((const int*)src_raw)[e];
            ti = ((const int*)tgt_raw)[e];
        }
        so[m] = (unsigned)si * HID;
        to[m] = (unsigned)ti * HID;
    }

    f32x4 acc[2][8];
#pragma unroll
    for (int m = 0; m < 2; ++m)
#pragma unroll
        for (int n = 0; n < 8; ++n)
            acc[m][n] = (f32x4){0.f, 0.f, 0.f, 0.f};

    const int koff = g * 8;
#pragma unroll
    for (int f = 0; f < 8; ++f) {
        short8 afr[2];
        const int k0 = (f & 3) * 32 + koff;
#pragma unroll
        for (int m = 0; m < 2; ++m) {
            const unsigned off = (f < 4 ? so[m] : to[m]) + k0;
            if (MODE == 0) {
                afr[m] = *reinterpret_cast<const short8*>(bemb + off);
            } else {
                f32x4 x0 = *reinterpret_cast<const f32x4*>(emb + off);
                f32x4 x1 = *reinterpret_cast<const f32x4*>(emb + off + 4);
                short8 t;
#pragma unroll
                for (int j = 0; j < 4; ++j) {
                    t[j]     = f2bf(x0[j]);
                    t[4 + j] = f2bf(x1[j]);
                }
                afr[m] = t;
            }
        }
#pragma unroll
        for (int n = 0; n < 8; ++n) {
            short8 bfr = *reinterpret_cast<const short8*>(&lds_b[((n * 8 + f) * 64 + l) * 8]);
#pragma unroll
            for (int m = 0; m < 2; ++m)
                acc[m][n] = __builtin_amdgcn_mfma_f32_16x16x32_bf16(afr[m], bfr, acc[m][n], 0, 0, 0);
        }
    }

    float b1v[8], w2v[8];
#pragma unroll
    for (int n = 0; n < 8; ++n) {
        b1v[n] = b1[n * 16 + c];
        w2v[n] = W2[n * 16 + c];
    }
    const float b2s = b2[0];

#pragma unroll
    for (int m = 0; m < 2; ++m) {
        float s[4] = {0.f, 0.f, 0.f, 0.f};
#pragma unroll
        for (int n = 0; n < 8; ++n) {
#pragma unroll
            for (int r = 0; r < 4; ++r)
                s[r] += fmaxf(acc[m][n][r] + b1v[n], 0.f) * w2v[n];
        }
#pragma unroll
        for (int w = 1; w < 16; w <<= 1) {
#pragma unroll
            for (int r = 0; r < 4; ++r)
                s[r] += __shfl_xor(s[r], w, 16);
        }
        if (c == 0) {
            const long long eb = e0 + m * 16 + g * 4;
#pragma unroll
            for (int r = 0; r < 4; ++r)
                if (eb + r < E) out[eb + r] = s[r] + b2s;
        }
    }
}

extern "C" void kernel_launch(void* const* d_in, const int* in_sizes, int n_in,
                              void* d_out, int out_size, void* d_ws, size_t ws_size,
                              hipStream_t stream) {
    const float* emb = (const float*)d_in[0];
    const void*  src = d_in[1];
    const void*  tgt = d_in[2];
    // d_in[3] = edge_type_idx (selector; params passed are already the selected ones)
    const float* W1 = (const float*)d_in[4];
    const float* b1 = (const float*)d_in[5];
    const float* W2 = (const float*)d_in[6];
    const float* b2 = (const float*)d_in[7];
    float* out = (float*)d_out;

    const int E  = in_sizes[1];
    const int Nn = in_sizes[0] / HID;

    const size_t uv_bytes = (size_t)Nn * HID * sizeof(short);
    // layout: bpk2 64K | gh[8]+cursor[8] | pad to 64K+4K | U | V | rec
    const size_t off_gh   = 65536;
    const size_t off_U    = 65536 + 4096;
    const size_t off_V    = off_U + uv_bytes;
    const size_t off_rec  = off_V + uv_bytes;
    const size_t need_part = off_rec + (size_t)E * 8;
    const size_t need_uv   = 65536 + 2 * uv_bytes;
    const size_t need_old  = 65536 + (size_t)in_sizes[0] * sizeof(short);

    const bool packable = (Nn <= (1 << 17)) && (E <= (1 << 21));

    if (ws_size >= need_part && E >= 4096 && packable) {
        short*              bpk2   = (short*)d_ws;
        int*                gh     = (int*)((char*)d_ws + off_gh);
        int*                cursor = gh + 8;
        unsigned short*     U      = (unsigned short*)((char*)d_ws + off_U);
        unsigned short*     Vv     = (unsigned short*)((char*)d_ws + off_V);
        unsigned long long* rec    = (unsigned long long*)((char*)d_ws + off_rec);

        const float bscale = 7.9999f / (float)Nn;

        hipMemsetAsync(gh, 0, 64, stream);
        hist_pack_kernel<<<256, 256, 0, stream>>>(W1, bpk2, src, tgt, E, bscale, gh);
        uv_kernel<<<(Nn + 127) / 128, 512, 0, stream>>>(emb, bpk2, U, Vv, Nn);
        scatter8_kernel<<<(E + 2047) / 2048, 256, 0, stream>>>(
            src, tgt, E, bscale, gh, cursor, rec);
        const int per_x = (E / 8 + 8192) / 128 + 1;
        edge_pass_part_kernel<<<per_x * 8, 256, 0, stream>>>(
            U, Vv, rec, gh, b1, W2, b2, out, per_x);
        return;
    }

    if (ws_size >= need_uv) {
        short*          bpk2 = (short*)d_ws;
        unsigned short* U    = (unsigned short*)((char*)d_ws + 65536);
        unsigned short* Vv   = (unsigned short*)((char*)d_ws + 65536 + uv_bytes);

        hist_pack_kernel<<<16, 256, 0, stream>>>(W1, bpk2, src, tgt, 0, 1.0f, nullptr);
        uv_kernel<<<(Nn + 127) / 128, 512, 0, stream>>>(emb, bpk2, U, Vv, Nn);
        edge_pass_kernel<<<(E + 63) / 64, 256, 0, stream>>>(U, Vv, src, tgt, b1, W2, b2, out, E);
        return;
    }

    // ---- fallback: R3 gathered-MFMA path
    short* bpk  = (short*)d_ws;
    short* bemb = (short*)((char*)d_ws + 65536);

    int mode;
    if (ws_size >= need_old)        mode = 0;
    else if (ws_size >= 65536)      mode = 1;
    else                            mode = 2;

    if (mode != 2)
        pack_w1_kernel<<<16, 256, 0, stream>>>(W1, bpk);
    if (mode == 0) {
        const int n8 = in_sizes[0] / 8;
        conv_emb_kernel<<<(n8 + 255) / 256, 256, 0, stream>>>(emb, bemb, n8);
    }

    const int grid = (E + 255) / 256;
    if (mode == 0)
        edge_head_kernel<0><<<grid, 512, 0, stream>>>(emb, bemb, src, tgt, W1, b1, W2, b2, bpk, out, E);
    else if (mode == 1)
        edge_head_kernel<1><<<grid, 512, 0, stream>>>(emb, bemb, src, tgt, W1, b1, W2, b2, bpk, out, E);
    else
        edge_head_kernel<2><<<grid, 512, 0, stream>>>(emb, bemb, src, tgt, W1, b1, W2, b2, bpk, out, E);
}

// Round 20
// 141.343 us; speedup vs baseline: 1.1286x; 1.1286x over previous
//
#include <hip/hip_runtime.h>
#include <hip/hip_bf16.h>

#define HID 128

typedef __attribute__((ext_vector_type(8))) short short8;
typedef __attribute__((ext_vector_type(4))) float f32x4;
typedef __attribute__((ext_vector_type(16))) float f32x16;
typedef __attribute__((ext_vector_type(4))) unsigned int u32x4;
typedef __attribute__((ext_vector_type(2))) _Float16 h2;

__device__ __forceinline__ short f2bf(float x) {
    __bf16 b = (__bf16)x;
    return __builtin_bit_cast(short, b);
}
__device__ __forceinline__ float bf2f(short s) {
    unsigned u = (unsigned)(unsigned short)s << 16;
    return __builtin_bit_cast(float, u);
}

// ===========================================================================
// FINAL (revert to R12, best measured: 141.2us).
// FACTORED PATH: U = emb@W1[:128], V = emb@W1[128:] (dense per-node GEMM),
// then out[e] = relu(U[src]+V[tgt]+b1)@W2 + b2 (gather + packed-fp16 VALU).
// U/V stored as fp16 (same bytes as bf16, more mantissa, enables v_pk_* ops).
//
// 19-round search summary: partitioned variants (R13-R19) cut the edge pass
// 109->77us (FETCH 375->200MB) but the reorder prefix costs >= what it saves.
// Edge pass here runs at ~3.5TB/s effective random-gather BW (44% HBM peak,
// ~55% of streaming ceiling at 256B granules), occupancy 84% — the
// structural floor for this bipartite gather. uv prepass is BW-bound.
// ===========================================================================

// ---------------------------------------------------------------------------
// Pack W1 halves into 32x32x16 MFMA-B fragment order (bf16), both halves:
// bpk2[(((half*4+nt)*8+ks)*64+l)*8+j]
//   = bf16( W1[(half*128 + ks*16 + (l>>5)*8 + j)*128 + nt*32 + (l&31)] )
// ---------------------------------------------------------------------------
__global__ void pack_w1_uv_kernel(const float* __restrict__ W1, short* __restrict__ bpk2) {
    int t = blockIdx.x * 256 + threadIdx.x;   // 0..4095 = half*2048 + nt*512 + ks*64 + l
    int l    = t & 63;
    int ks   = (t >> 6) & 7;
    int nt   = (t >> 9) & 3;
    int half = t >> 11;
    int k0  = half * 128 + ks * 16 + (l >> 5) * 8;
    int col = nt * 32 + (l & 31);
    short8 v;
#pragma unroll
    for (int j = 0; j < 8; ++j)
        v[j] = f2bf(W1[(k0 + j) * HID + col]);
    *reinterpret_cast<short8*>(&bpk2[t * 8]) = v;
}

// ---------------------------------------------------------------------------
// UV precompute: U[n][c] = fp16( sum_k bf16(emb[n][k]) * bf16(W1a[k][c]) ),
// same for V with W1b. Block = 512 thr = 8 waves = 4 node-groups x 2 col-
// groups = 128 nodes/block. mfma_f32_32x32x16_bf16, acc = 2(U/V)x2(n)x16.
// ---------------------------------------------------------------------------
__global__ __launch_bounds__(512, 4) void uv_kernel(
    const float* __restrict__ emb,
    const short* __restrict__ bpk2,
    unsigned short* __restrict__ U,
    unsigned short* __restrict__ V,
    int Nn)
{
    __shared__ short lds_b[32768];   // 64 KB packed W1 (both halves)

    const int tid = threadIdx.x;
    const int l   = tid & 63;
    const int wid = tid >> 6;
    const int wg  = wid >> 1;        // node-group 0..3
    const int wn  = wid & 1;         // col-group 0..1
    const int lc  = l & 31;
    const int hi  = l >> 5;

    {
        const u32x4* g = (const u32x4*)bpk2;
        u32x4* d = (u32x4*)lds_b;
#pragma unroll
        for (int i = 0; i < 8; ++i) d[i * 512 + tid] = g[i * 512 + tid];
    }
    __syncthreads();

    const int base = blockIdx.x * 128 + wg * 32;
    int nr = base + lc;
    if (nr >= Nn) nr = Nn - 1;

    f32x16 accU[2], accV[2];
#pragma unroll
    for (int n = 0; n < 2; ++n) { accU[n] = (f32x16)(0.f); accV[n] = (f32x16)(0.f); }

#pragma unroll
    for (int ks = 0; ks < 8; ++ks) {
        const float* p = emb + (size_t)nr * HID + ks * 16 + hi * 8;
        f32x4 x0 = *reinterpret_cast<const f32x4*>(p);
        f32x4 x1 = *reinterpret_cast<const f32x4*>(p + 4);
        short8 afr;
#pragma unroll
        for (int j = 0; j < 4; ++j) { afr[j] = f2bf(x0[j]); afr[4 + j] = f2bf(x1[j]); }
#pragma unroll
        for (int n = 0; n < 2; ++n) {
            const int nt = wn * 2 + n;
            short8 bU = *reinterpret_cast<const short8*>(&lds_b[(((0 + nt) * 8 + ks) * 64 + l) * 8]);
            short8 bV = *reinterpret_cast<const short8*>(&lds_b[(((4 + nt) * 8 + ks) * 64 + l) * 8]);
            accU[n] = __builtin_amdgcn_mfma_f32_32x32x16_bf16(afr, bU, accU[n], 0, 0, 0);
            accV[n] = __builtin_amdgcn_mfma_f32_32x32x16_bf16(afr, bV, accV[n], 0, 0, 0);
        }
    }

    // C layout (32x32): col = l&31, row = (r&3) + 8*(r>>2) + 4*hi
#pragma unroll
    for (int n = 0; n < 2; ++n) {
        const int col = wn * 64 + n * 32 + lc;
#pragma unroll
        for (int r = 0; r < 16; ++r) {
            const int row = (r & 3) + 8 * (r >> 2) + 4 * hi;
            const int node = base + row;
            if (node < Nn) {
                _Float16 hu = (_Float16)accU[n][r];
                _Float16 hv = (_Float16)accV[n][r];
                U[(size_t)node * HID + col] = __builtin_bit_cast(unsigned short, hu);
                V[(size_t)node * HID + col] = __builtin_bit_cast(unsigned short, hv);
            }
        }
    }
}

// ---------------------------------------------------------------------------
// Edge pass: out[e] = relu(U[src]+V[tgt]+b1)@W2 + b2 in packed fp16 (clang
// ext_vector _Float16: +,* -> v_pk_add/fma_f16, __builtin_elementwise_max ->
// v_pk_max_f16). 16 lanes/edge (8 cols each), 16 edges/wave, all 8 gathers
// issued up front. fp16 accumulates only 4 terms/lane before fp32 reduce.
// 32 VGPR -> ~84% occupancy; gather latency hidden by TLP+MLP.
// ---------------------------------------------------------------------------
__global__ __launch_bounds__(256) void edge_pass_kernel(
    const unsigned short* __restrict__ U,
    const unsigned short* __restrict__ V,
    const void* __restrict__ src_raw,
    const void* __restrict__ tgt_raw,
    const float* __restrict__ b1,
    const float* __restrict__ W2,
    const float* __restrict__ b2,
    float* __restrict__ out,
    int E)
{
    const int tid = threadIdx.x;
    const int l   = tid & 63;
    const int wid = tid >> 6;
    const int le  = l >> 4;          // edge slot in group (0..3)
    const int lc  = l & 15;          // col group: cols [lc*8, lc*8+8)

    // wave-parallel int64-vs-int32 index probe: int64 (<2^31) => all odd
    // dwords of the first 32 entries are zero.
    int oddw = 0;
    {
        const int* s32 = (const int*)src_raw;
        if (l < 32) oddw = s32[2 * l + 1];
    }
    const bool i64f = (__ballot(oddw != 0) == 0ULL);

    h2 b1p[4], w2p[4];
    {
        f32x4 a = *reinterpret_cast<const f32x4*>(b1 + lc * 8);
        f32x4 b = *reinterpret_cast<const f32x4*>(b1 + lc * 8 + 4);
        f32x4 c = *reinterpret_cast<const f32x4*>(W2 + lc * 8);
        f32x4 d = *reinterpret_cast<const f32x4*>(W2 + lc * 8 + 4);
#pragma unroll
        for (int j = 0; j < 2; ++j) {
            b1p[0][j] = (_Float16)a[j];     b1p[1][j] = (_Float16)a[2 + j];
            b1p[2][j] = (_Float16)b[j];     b1p[3][j] = (_Float16)b[2 + j];
            w2p[0][j] = (_Float16)c[j];     w2p[1][j] = (_Float16)c[2 + j];
            w2p[2][j] = (_Float16)d[j];     w2p[3][j] = (_Float16)d[2 + j];
        }
    }
    const float b2s = b2[0];
    const h2 zero2 = (h2)((_Float16)0.f);

    const long long ebase = ((long long)blockIdx.x * 4 + wid) * 16;

    short8 ub[4], vb[4];
#pragma unroll
    for (int g = 0; g < 4; ++g) {
        long long e = ebase + g * 4 + le;
        if (e >= E) e = E - 1;
        long long si, ti;
        if (i64f) {
            si = ((const long long*)src_raw)[e];
            ti = ((const long long*)tgt_raw)[e];
        } else {
            si = ((const int*)src_raw)[e];
            ti = ((const int*)tgt_raw)[e];
        }
        ub[g] = *reinterpret_cast<const short8*>(U + (unsigned)si * HID + lc * 8);
        vb[g] = *reinterpret_cast<const short8*>(V + (unsigned)ti * HID + lc * 8);
    }

#pragma unroll
    for (int g = 0; g < 4; ++g) {
        const unsigned int* uw = (const unsigned int*)&ub[g];
        const unsigned int* vw = (const unsigned int*)&vb[g];
        h2 s2 = zero2;
#pragma unroll
        for (int j = 0; j < 4; ++j) {
            h2 hu = __builtin_bit_cast(h2, uw[j]);
            h2 hv = __builtin_bit_cast(h2, vw[j]);
            h2 h  = hu + hv + b1p[j];
            h = __builtin_elementwise_max(h, zero2);
            s2 = s2 + h * w2p[j];
        }
        float s = (float)s2[0] + (float)s2[1];
#pragma unroll
        for (int w = 1; w < 16; w <<= 1)
            s += __shfl_xor(s, w, 16);
        const long long e = ebase + g * 4 + le;
        if (lc == 0 && e < E)
            out[e] = s + b2s;
    }
}

// ===========================================================================
// FALLBACK PATH (R3): MFMA over gathered rows (bf16), for small ws.
// ===========================================================================

__global__ void pack_w1_kernel(const float* __restrict__ W1, short* __restrict__ bpk) {
    int t = blockIdx.x * 256 + threadIdx.x;   // 0..4095 = n*512 + f*64 + l
    int f = (t >> 6) & 7;
    int l = t & 63;
    int n = t >> 9;
    int c = l & 15, kb = l >> 4;
    int k0 = f * 32 + kb * 8;
    short8 v;
#pragma unroll
    for (int j = 0; j < 8; ++j)
        v[j] = f2bf(W1[(k0 + j) * HID + n * 16 + c]);
    *reinterpret_cast<short8*>(&bpk[t * 8]) = v;
}

__global__ __launch_bounds__(256) void conv_emb_kernel(
    const float* __restrict__ emb, short* __restrict__ bemb, int n8) {
    int i = blockIdx.x * 256 + threadIdx.x;
    if (i >= n8) return;
    f32x4 x0 = *reinterpret_cast<const f32x4*>(emb + (size_t)i * 8);
    f32x4 x1 = *reinterpret_cast<const f32x4*>(emb + (size_t)i * 8 + 4);
    short8 v;
#pragma unroll
    for (int j = 0; j < 4; ++j) {
        v[j]     = f2bf(x0[j]);
        v[4 + j] = f2bf(x1[j]);
    }
    *reinterpret_cast<short8*>(&bemb[(size_t)i * 8]) = v;
}

template <int MODE>
__global__ __launch_bounds__(512, 4) void edge_head_kernel(
    const float* __restrict__ emb,
    const short* __restrict__ bemb,
    const void* __restrict__ src_raw,
    const void* __restrict__ tgt_raw,
    const float* __restrict__ W1,
    const float* __restrict__ b1,
    const float* __restrict__ W2,
    const float* __restrict__ b2,
    const short* __restrict__ bpk,
    float* __restrict__ out,
    int E)
{
    __shared__ short lds_b[32768];

    const int tid = threadIdx.x;

    int i64f = 1;
    {
        const int* s32 = (const int*)src_raw;
#pragma unroll
        for (int i = 1; i < 32; i += 2) i64f &= (s32[i] == 0);
    }

    if (MODE != 2) {
        const u32x4* g = (const u32x4*)bpk;
        u32x4* d = (u32x4*)lds_b;
#pragma unroll
        for (int i = 0; i < 8; ++i) d[i * 512 + tid] = g[i * 512 + tid];
    } else {
        for (int i = 0; i < 64; ++i) {
            int idx = i * 512 + tid;
            int col = idx & 127;
            int k   = idx >> 7;
            int n = col >> 4, cc = col & 15;
            int f = k >> 5, kb = (k >> 3) & 3, j = k & 7;
            int l2 = kb * 16 + cc;
            lds_b[(((n * 8 + f) * 64 + l2) << 3) + j] = f2bf(W1[idx]);
        }
    }
    __syncthreads();

    const int l = tid & 63;
    const int wid = tid >> 6;
    const int c = l & 15;
    const int g = l >> 4;
    const long long e0 = (long long)blockIdx.x * 256 + wid * 32;

    unsigned so[2], to[2];
#pragma unroll
    for (int m = 0; m < 2; ++m) {
        long long e = e0 + m * 16 + c;
        if (e >= E) e = E - 1;
        long long si, ti;
        if (i64f) {
            si = ((const long long*)src_raw)[e];
            ti = ((const long long*)tgt_raw)[e];
        } else {
            si = ((const int*)src_raw)[e];
            ti = ((const int*)tgt_raw)[e];
        }
        so[m] = (unsigned)si * HID;
        to[m] = (unsigned)ti * HID;
    }

    f32x4 acc[2][8];
#pragma unroll
    for (int m = 0; m < 2; ++m)
#pragma unroll
        for (int n = 0; n < 8; ++n)
            acc[m][n] = (f32x4){0.f, 0.f, 0.f, 0.f};

    const int koff = g * 8;
#pragma unroll
    for (int f = 0; f < 8; ++f) {
        short8 afr[2];
        const int k0 = (f & 3) * 32 + koff;
#pragma unroll
        for (int m = 0; m < 2; ++m) {
            const unsigned off = (f < 4 ? so[m] : to[m]) + k0;
            if (MODE == 0) {
                afr[m] = *reinterpret_cast<const short8*>(bemb + off);
            } else {
                f32x4 x0 = *reinterpret_cast<const f32x4*>(emb + off);
                f32x4 x1 = *reinterpret_cast<const f32x4*>(emb + off + 4);
                short8 t;
#pragma unroll
                for (int j = 0; j < 4; ++j) {
                    t[j]     = f2bf(x0[j]);
                    t[4 + j] = f2bf(x1[j]);
                }
                afr[m] = t;
            }
        }
#pragma unroll
        for (int n = 0; n < 8; ++n) {
            short8 bfr = *reinterpret_cast<const short8*>(&lds_b[((n * 8 + f) * 64 + l) * 8]);
#pragma unroll
            for (int m = 0; m < 2; ++m)
                acc[m][n] = __builtin_amdgcn_mfma_f32_16x16x32_bf16(afr[m], bfr, acc[m][n], 0, 0, 0);
        }
    }

    float b1v[8], w2v[8];
#pragma unroll
    for (int n = 0; n < 8; ++n) {
        b1v[n] = b1[n * 16 + c];
        w2v[n] = W2[n * 16 + c];
    }
    const float b2s = b2[0];

#pragma unroll
    for (int m = 0; m < 2; ++m) {
        float s[4] = {0.f, 0.f, 0.f, 0.f};
#pragma unroll
        for (int n = 0; n < 8; ++n) {
#pragma unroll
            for (int r = 0; r < 4; ++r)
                s[r] += fmaxf(acc[m][n][r] + b1v[n], 0.f) * w2v[n];
        }
#pragma unroll
        for (int w = 1; w < 16; w <<= 1) {
#pragma unroll
            for (int r = 0; r < 4; ++r)
                s[r] += __shfl_xor(s[r], w, 16);
        }
        if (c == 0) {
            const long long eb = e0 + m * 16 + g * 4;
#pragma unroll
            for (int r = 0; r < 4; ++r)
                if (eb + r < E) out[eb + r] = s[r] + b2s;
        }
    }
}

extern "C" void kernel_launch(void* const* d_in, const int* in_sizes, int n_in,
                              void* d_out, int out_size, void* d_ws, size_t ws_size,
                              hipStream_t stream) {
    const float* emb = (const float*)d_in[0];
    const void*  src = d_in[1];
    const void*  tgt = d_in[2];
    // d_in[3] = edge_type_idx (selector; params passed are already the selected ones)
    const float* W1 = (const float*)d_in[4];
    const float* b1 = (const float*)d_in[5];
    const float* W2 = (const float*)d_in[6];
    const float* b2 = (const float*)d_in[7];
    float* out = (float*)d_out;

    const int E  = in_sizes[1];
    const int Nn = in_sizes[0] / HID;          // node count

    const size_t uv_bytes   = (size_t)Nn * HID * sizeof(short);
    const size_t need_uv    = 65536 + 2 * uv_bytes;
    const size_t need_old   = 65536 + (size_t)in_sizes[0] * sizeof(short);

    if (ws_size >= need_uv) {
        // ---- factored path: pack W1 -> UV precompute -> edge pass
        short*          bpk2 = (short*)d_ws;
        unsigned short* U    = (unsigned short*)((char*)d_ws + 65536);
        unsigned short* Vv   = (unsigned short*)((char*)d_ws + 65536 + uv_bytes);

        pack_w1_uv_kernel<<<16, 256, 0, stream>>>(W1, bpk2);
        uv_kernel<<<(Nn + 127) / 128, 512, 0, stream>>>(emb, bpk2, U, Vv, Nn);
        edge_pass_kernel<<<(E + 63) / 64, 256, 0, stream>>>(U, Vv, src, tgt, b1, W2, b2, out, E);
        return;
    }

    // ---- fallback: R3 gathered-MFMA path
    short* bpk  = (short*)d_ws;
    short* bemb = (short*)((char*)d_ws + 65536);

    int mode;
    if (ws_size >= need_old)        mode = 0;
    else if (ws_size >= 65536)      mode = 1;
    else                            mode = 2;

    if (mode != 2)
        pack_w1_kernel<<<16, 256, 0, stream>>>(W1, bpk);
    if (mode == 0) {
        const int n8 = in_sizes[0] / 8;
        conv_emb_kernel<<<(n8 + 255) / 256, 256, 0, stream>>>(emb, bemb, n8);
    }

    const int grid = (E + 255) / 256;
    if (mode == 0)
        edge_head_kernel<0><<<grid, 512, 0, stream>>>(emb, bemb, src, tgt, W1, b1, W2, b2, bpk, out, E);
    else if (mode == 1)
        edge_head_kernel<1><<<grid, 512, 0, stream>>>(emb, bemb, src, tgt, W1, b1, W2, b2, bpk, out, E);
    else
        edge_head_kernel<2><<<grid, 512, 0, stream>>>(emb, bemb, src, tgt, W1, b1, W2, b2, bpk, out, E);
}